// Round 8
// baseline (588.422 us; speedup 1.0000x reference)
//
#include <hip/hip_runtime.h>
#include <hip/hip_fp16.h>

#define NNODES   4000
#define TSTEPS   32
#define HDIM     64
#define ECOUNT   1024000
#define NTOT     128000        // NNODES * TSTEPS
#define BATCHB   8
#define NNEUR    500
#define TEBD     16
#define NSTEPS   12

#define REC_BLOCKS  (NNODES / 16)    // 250
#define HIST_BLOCKS (ECOUNT / 256)   // 4000: 1 edge/thread fire-and-forget

// edge-centric accumulation geometry
#define EPB          2048            // edges per block; 500 * 2048 == ECOUNT
#define EDGE_BLOCKS  500
#define NBT          256             // pooling groups (= NTOT/500)
#define PPART        (NBT * HDIM)    // 16384 floats = 64 KB per block partial

typedef _Float16 half8_t __attribute__((ext_vector_type(8)));
typedef float    f32x4_t __attribute__((ext_vector_type(4)));

__device__ __forceinline__ float sigmoidf_(float x) {
    return 1.0f / (1.0f + __expf(-x));
}
__device__ __forceinline__ float tanhf_(float x) {
    return 1.0f - 2.0f / (1.0f + __expf(2.0f * x));
}

// ---------------- fused: MFMA GRU recurrence (blocks 0..249) +
//                  fp32 degree-sum histogram (blocks 250..4249) -----------
// Round-6 decision: the se32 bucket structure (and with it ~65 MB of
// line-granular scatter writes that provably never merge across XCDs,
// rounds 2/4) is ELIMINATED. Downstream only needs S[bt]=sum over 500
// consecutive rows (reference reshape semantics verified: group (b,tt)
// = rows [(b*32+tt)*500, +500) exactly), so edges can be consumed
// UNORDERED by k_edges. The histogram is now a bare fire-and-forget fp32
// atomicAdd of sum(w) per dst: no returned value (no L2 round-trip
// dependency), no scatter store.
// Round-3 lesson kept: no __threadfence() in hot per-block paths.
// Recurrence: one block (4 waves) owns 16 nodes for all 32 timesteps; wave
// wv owns the 16-feature stripe of each gate. Weight B-frags in VGPRs; LDS
// only a 2x(16x72) fp16 ping-pong for the C->A h transpose; 1 barrier/step.
// Fragment layouts (gfx950 16x16x32): A[m=lane&15][k=quad*8+j],
// B[k=quad*8+j][n=lane&15], C[m=quad*4+reg][n=lane&15].
__global__ __launch_bounds__(256) void k_recHist(
    const float* __restrict__ x, const float* __restrict__ Wih,
    const float* __restrict__ Whh, const float* __restrict__ bih,
    const float* __restrict__ bhh, const float* __restrict__ Wg,
    _Float16* __restrict__ xwh,
    const int* __restrict__ ei, const float* __restrict__ ea,
    float* __restrict__ dw)
{
    __shared__ __align__(16) _Float16 hbuf[2][16 * 72];   // stride 72: conflict-free

    const int tid = threadIdx.x;

    if (blockIdx.x >= REC_BLOCKS) {
        // -------- degree histogram: 1 edge/thread, fire-and-forget --------
        int e = (blockIdx.x - REC_BLOCKS) * 256 + tid;   // covers exactly ECOUNT
        atomicAdd(&dw[ei[ECOUNT + e]], ea[e]);
        return;
    }

    // -------- recurrence path --------
    const int lane = tid & 63;
    const int wv   = tid >> 6;       // feature tile 0..3
    const int c    = lane & 15;
    const int quad = lane >> 4;
    const int n0   = blockIdx.x * 16;

    auto makeB = [&](const float* W, int row, int k0) -> half8_t {
        const float4* p = (const float4*)(W + (size_t)row * HDIM + k0);
        float4 u = p[0], v = p[1];
        half8_t h;
        h[0] = (_Float16)u.x; h[1] = (_Float16)u.y; h[2] = (_Float16)u.z; h[3] = (_Float16)u.w;
        h[4] = (_Float16)v.x; h[5] = (_Float16)v.y; h[6] = (_Float16)v.z; h[7] = (_Float16)v.w;
        return h;
    };

    half8_t Bxr[2], Bxz[2], Bxn[2], Bhr[2], Bhz[2], Bhn[2], Bw[2];
#pragma unroll
    for (int kt = 0; kt < 2; ++kt) {
        int k0 = kt * 32 + quad * 8;
        Bxr[kt] = makeB(Wih, wv * 16 + c, k0);
        Bxz[kt] = makeB(Wih, 64 + wv * 16 + c, k0);
        Bxn[kt] = makeB(Wih, 128 + wv * 16 + c, k0);
        Bhr[kt] = makeB(Whh, wv * 16 + c, k0);
        Bhz[kt] = makeB(Whh, 64 + wv * 16 + c, k0);
        Bhn[kt] = makeB(Whh, 128 + wv * 16 + c, k0);
        Bw[kt]  = makeB(Wg, wv * 16 + c, k0);
    }

    const int f = wv * 16 + c;
    const float brz_r = bih[f] + bhh[f];
    const float brz_z = bih[64 + f] + bhh[64 + f];
    const float bin_  = bih[128 + f];
    const float bhn_  = bhh[128 + f];

    float hreg[4] = {0.f, 0.f, 0.f, 0.f};
    half8_t ah[2];

    const float* xp = x + (size_t)(n0 + c) * (TSTEPS * HDIM) + quad * 8;

    float4 xq0[4], xq1[4];
    {
        const float* p0 = xp;
        xq0[0] = *(const float4*)(p0);      xq0[1] = *(const float4*)(p0 + 4);
        xq0[2] = *(const float4*)(p0 + 32); xq0[3] = *(const float4*)(p0 + 36);
        const float* p1 = xp + HDIM;
        xq1[0] = *(const float4*)(p1);      xq1[1] = *(const float4*)(p1 + 4);
        xq1[2] = *(const float4*)(p1 + 32); xq1[3] = *(const float4*)(p1 + 36);
    }

    auto step = [&](int t, float4* xq) {
        half8_t ax[2];
#pragma unroll
        for (int kt = 0; kt < 2; ++kt) {
            float4 u = xq[kt * 2], v = xq[kt * 2 + 1];
            half8_t a;
            a[0] = (_Float16)u.x; a[1] = (_Float16)u.y; a[2] = (_Float16)u.z; a[3] = (_Float16)u.w;
            a[4] = (_Float16)v.x; a[5] = (_Float16)v.y; a[6] = (_Float16)v.z; a[7] = (_Float16)v.w;
            ax[kt] = a;
        }
        if (t + 2 < TSTEPS) {
            const float* pt = xp + (size_t)(t + 2) * HDIM;
            xq[0] = *(const float4*)(pt);      xq[1] = *(const float4*)(pt + 4);
            xq[2] = *(const float4*)(pt + 32); xq[3] = *(const float4*)(pt + 36);
        }

        f32x4_t Cr  = (f32x4_t){0.f, 0.f, 0.f, 0.f};
        f32x4_t Cz  = (f32x4_t){0.f, 0.f, 0.f, 0.f};
        f32x4_t Cnx = (f32x4_t){0.f, 0.f, 0.f, 0.f};
        f32x4_t Cnh = (f32x4_t){0.f, 0.f, 0.f, 0.f};

#pragma unroll
        for (int kt = 0; kt < 2; ++kt) {
            Cr  = __builtin_amdgcn_mfma_f32_16x16x32_f16(ax[kt], Bxr[kt], Cr, 0, 0, 0);
            Cz  = __builtin_amdgcn_mfma_f32_16x16x32_f16(ax[kt], Bxz[kt], Cz, 0, 0, 0);
            Cnx = __builtin_amdgcn_mfma_f32_16x16x32_f16(ax[kt], Bxn[kt], Cnx, 0, 0, 0);
        }
        if (t > 0) {
#pragma unroll
            for (int kt = 0; kt < 2; ++kt) {
                Cr  = __builtin_amdgcn_mfma_f32_16x16x32_f16(ah[kt], Bhr[kt], Cr, 0, 0, 0);
                Cz  = __builtin_amdgcn_mfma_f32_16x16x32_f16(ah[kt], Bhz[kt], Cz, 0, 0, 0);
                Cnh = __builtin_amdgcn_mfma_f32_16x16x32_f16(ah[kt], Bhn[kt], Cnh, 0, 0, 0);
            }
        }

        _Float16* hb = hbuf[t & 1];
#pragma unroll
        for (int r = 0; r < 4; ++r) {
            float rr = sigmoidf_(Cr[r] + brz_r);
            float zz = sigmoidf_(Cz[r] + brz_z);
            float nn = tanhf_(Cnx[r] + bin_ + rr * (Cnh[r] + bhn_));
            float hn = (1.0f - zz) * nn + zz * hreg[r];
            hreg[r] = hn;
            hb[(quad * 4 + r) * 72 + f] = (_Float16)hn;
        }

        __syncthreads();

#pragma unroll
        for (int kt = 0; kt < 2; ++kt)
            ah[kt] = *(half8_t*)&hb[c * 72 + kt * 32 + quad * 8];

        f32x4_t Cw = (f32x4_t){0.f, 0.f, 0.f, 0.f};
#pragma unroll
        for (int kt = 0; kt < 2; ++kt)
            Cw = __builtin_amdgcn_mfma_f32_16x16x32_f16(ah[kt], Bw[kt], Cw, 0, 0, 0);

#pragma unroll
        for (int r = 0; r < 4; ++r) {
            int row = (n0 + quad * 4 + r) * TSTEPS + t;
            xwh[(size_t)row * HDIM + f] = (_Float16)Cw[r];
        }
    };

#pragma unroll 1
    for (int tt = 0; tt < TSTEPS; tt += 2) {
        step(tt, xq0);
        step(tt + 1, xq1);
    }
}

// ---------------- unordered edge-centric S accumulation -------------------
// Each block consumes 2048 raw edges and accumulates c_e * xw[src] into an
// LDS acc[256 bt][64 h] (64 KB -> 2 blocks/CU). Per wave super-pass of 64
// edges: each lane loads ITS OWN edge's meta coalesced + 2 parallel random
// dw lookups (L2-resident 512 KB) and computes the full fp32 coefficient
// c = dis[s]*w*dis[d]; then 8-lanes-per-edge split: lane (j=lane>>3,
// sub=lane&7) handles slot u's edge (srcLane u*8+j via __shfl) and loads a
// 16 B half8 row segment -> 8 INDEPENDENT 128 B row loads in flight per
// wave (round-5 had 2 serial -> 386 us; this is the fix). ds_add order is
// j-staggered (k=(i+j)&7) so each step hits exactly 2 lanes/bank = free
// (m136). No global atomics; partial flushed coalesced (64 KB).
__global__ __launch_bounds__(256) void k_edges(
    const _Float16* __restrict__ xwh, const float* __restrict__ dw,
    const int* __restrict__ ei, const float* __restrict__ ea,
    float* __restrict__ Ppart)
{
    __shared__ float acc[PPART];     // 64 KB
    const int tid  = threadIdx.x;
    const int lane = tid & 63;
    const int wv   = tid >> 6;
    const int j    = lane >> 3;      // slot 0..7
    const int sub  = lane & 7;       // feature segment 0..7

    for (int i = tid; i < PPART; i += 256) acc[i] = 0.f;
    __syncthreads();

    const int ebase = blockIdx.x * EPB + wv * (EPB / 4);   // 512 edges/wave

#pragma unroll 1
    for (int g = 0; g < (EPB / 4) / 64; ++g) {             // 8 super-passes
        const int m = ebase + g * 64 + lane;               // own edge
        int   sO = ei[m];
        int   dO = ei[ECOUNT + m];
        float wO = ea[m];
        float cO = wO * rsqrtf(1.0f + dw[sO]) * rsqrtf(1.0f + dw[dO]);
        int   btO = (int)((unsigned)dO / 500u);

        // distribute slot edges + issue all 8 row loads (independent)
        half8_t vS[8];
        int sS[8];
#pragma unroll
        for (int u = 0; u < 8; ++u) {
            sS[u] = __shfl(sO, u * 8 + j);
            vS[u] = *(const half8_t*)&xwh[(size_t)sS[u] * HDIM + sub * 8];
        }
        float cS[8]; int btS[8];
#pragma unroll
        for (int u = 0; u < 8; ++u) {
            cS[u]  = __shfl(cO, u * 8 + j);
            btS[u] = __shfl(btO, u * 8 + j);
        }
#pragma unroll
        for (int u = 0; u < 8; ++u) {
            float* ap = &acc[btS[u] * HDIM + sub * 8];
#pragma unroll
            for (int i2 = 0; i2 < 8; ++i2) {
                int k = (i2 + j) & 7;          // stagger: 2 lanes/bank/step
                atomicAdd(&ap[k], cS[u] * (float)vS[u][k]);
            }
        }
    }

    __syncthreads();
    float* dst = Ppart + (size_t)blockIdx.x * PPART;
    for (int i = tid; i < PPART; i += 256) dst[i] = acc[i];
}

// ---------------- merge partials + self-loops into S ----------------------
// Block bt: sums Ppart[blk][bt*64+h] over the 500 edge-blocks (coalesced,
// 32 MB total) and adds the self-loop terms sum_{d in bt} xw[d][h]/(1+dw[d])
// for its 500 consecutive rows (16.4 MB coalesced). Writes S once.
__global__ __launch_bounds__(256) void k_merge(
    const float* __restrict__ Ppart, const _Float16* __restrict__ xwh,
    const float* __restrict__ dw, float* __restrict__ S)
{
    const int bt  = blockIdx.x;
    const int tid = threadIdx.x;
    const int h   = tid & 63;
    const int q   = tid >> 6;        // quarter 0..3

    float s = 0.f;
    const float* bp = Ppart + (size_t)bt * HDIM + h;
#pragma unroll 4
    for (int blk = q * 125; blk < q * 125 + 125; ++blk)
        s += bp[(size_t)blk * PPART];

    const int dbase = bt * NNEUR + q * 125;
#pragma unroll 1
    for (int r = 0; r < 125; ++r) {
        int d = dbase + r;
        float t = rsqrtf(1.0f + dw[d]);
        s += (t * t) * (float)xwh[(size_t)d * HDIM + h];   // dis^2 * xw
    }

    __shared__ float red[256];
    red[tid] = s;
    __syncthreads();
    if (tid < 64)
        S[bt * 64 + tid] = red[tid] + red[64 + tid] + red[128 + tid] + red[192 + tid];
}

// ---------------- attention MLP + pooling + FC head (one block) ----------------
__global__ __launch_bounds__(256) void k_final(
    const float* __restrict__ S, const float* __restrict__ W1,
    const float* __restrict__ W2, const float* __restrict__ fcW,
    const float* __restrict__ fcb, float* __restrict__ out)
{
    __shared__ float xt[256];
    __shared__ float a1[128];
    __shared__ float attn[256];
    __shared__ float pooled[512];
    const int tid = threadIdx.x;

    {
        float s = 0.f;
        const float* p = S + tid * 64;
#pragma unroll
        for (int hh = 0; hh < 64; ++hh) s += p[hh];
        xt[tid] = s * (1.0f / 32000.0f);
    }
    __syncthreads();
    if (tid < 128) {
        int b = tid >> 4, i = tid & 15;
        float s = 0.f;
#pragma unroll
        for (int t = 0; t < 32; ++t) s += xt[b * 32 + t] * W1[i * 32 + t];
        a1[tid] = fmaxf(s, 0.f);
    }
    __syncthreads();
    {
        int b = tid >> 5, t = tid & 31;
        float s = 0.f;
#pragma unroll
        for (int i = 0; i < 16; ++i) s += a1[b * 16 + i] * W2[t * 16 + i];
        attn[tid] = 1.0f / (1.0f + __expf(-s));
    }
    __syncthreads();
    for (int o = tid; o < 512; o += 256) {
        int b = o >> 6, h = o & 63;
        float s = 0.f;
#pragma unroll
        for (int t = 0; t < 32; ++t) s += attn[b * 32 + t] * S[(b * 32 + t) * 64 + h];
        pooled[o] = s;
    }
    __syncthreads();
    if (tid < BATCHB * NSTEPS) {
        int b = tid / NSTEPS, st = tid % NSTEPS;
        float acc = fcb[st];
#pragma unroll
        for (int h = 0; h < 64; ++h) acc += pooled[b * 64 + h] * fcW[st * 64 + h];
        out[b * NSTEPS + st] = acc;
    }
}

extern "C" void kernel_launch(void* const* d_in, const int* in_sizes, int n_in,
                              void* d_out, int out_size, void* d_ws, size_t ws_size,
                              hipStream_t stream) {
    const float* x   = (const float*)d_in[0];
    const int*   ei  = (const int*)  d_in[1];
    const float* ea  = (const float*)d_in[2];
    // d_in[3] = batch: unused by the reference computation
    const float* Wih = (const float*)d_in[4];
    const float* Whh = (const float*)d_in[5];
    const float* bih = (const float*)d_in[6];
    const float* bhh = (const float*)d_in[7];
    const float* Wg  = (const float*)d_in[8];
    const float* W1  = (const float*)d_in[9];
    const float* W2  = (const float*)d_in[10];
    const float* fcW = (const float*)d_in[11];
    const float* fcb = (const float*)d_in[12];
    float* out = (float*)d_out;

    // workspace layout (~49.7 MB)
    char* p = (char*)d_ws;
    float* dw = (float*)p;         p += sizeof(float) * NTOT;                                       // 512 KB
    float* S  = (float*)p;         p += sizeof(float) * NBT * HDIM;                                 // 64 KB
    float* Ppart = (float*)p;      p += sizeof(float) * (size_t)EDGE_BLOCKS * PPART;                // 32.77 MB
    _Float16* xwh = (_Float16*)p;  p += sizeof(_Float16) * (size_t)NTOT * HDIM;                     // 16.38 MB

    hipMemsetAsync(dw, 0, sizeof(float) * NTOT, stream);
    k_recHist <<<REC_BLOCKS + HIST_BLOCKS, 256, 0, stream>>>(
        x, Wih, Whh, bih, bhh, Wg, xwh, ei, ea, dw);
    k_edges   <<<EDGE_BLOCKS, 256, 0, stream>>>(xwh, dw, ei, ea, Ppart);
    k_merge   <<<NBT, 256, 0, stream>>>(Ppart, xwh, dw, S);
    k_final   <<<1, 256, 0, stream>>>(S, W1, W2, fcW, fcb, out);
}

// Round 9
// 238.563 us; speedup vs baseline: 2.4665x; 2.4665x over previous
//
#include <hip/hip_runtime.h>
#include <hip/hip_fp16.h>

#define NNODES   4000
#define TSTEPS   32
#define HDIM     64
#define ECOUNT   1024000
#define NTOT     128000        // NNODES * TSTEPS
#define BATCHB   8
#define NNEUR    500
#define TEBD     16
#define NSTEPS   12

// packed u32 histogram cell: count in [31:23] (<=511), sum(w) fixed-point
// 2^-18 in [22:0] (max 32.0, needs 5 int bits; deg err <= ~2e-5, harmless)
#define CNT_SHIFT 23
#define SUM_MASK  0x7FFFFFu
#define SUM_SCALE 262144.0f    // 2^18
#define SLOTS     32           // fixed bucket stride; P(indeg>32) ~ 1e-10 (Poisson mean 8)
#define REC_BLOCKS  (NNODES / 16)    // 250

// XCD-sharded histogram: 8 families (slice = blockIdx%8), each family scans
// the whole edge list in 1024-edge chunks and keeps only dsts in its slice.
#define SLICE       16000            // NTOT / 8
#define CHUNK       1024
#define HIST_BLOCKS (ECOUNT / CHUNK * 8)   // 8000

#define SCALE_BLOCKS (NTOT * HDIM / 8 / 256)  // 4000

#define ROWS_PER_WAVE  5       // gather: rows per wave; 20 rows/block, 20 | 500
#define ROWS_PER_BLOCK 20
#define GATHER_BLOCKS  (NTOT / ROWS_PER_BLOCK)   // 6400

typedef _Float16 half8_t __attribute__((ext_vector_type(8)));
typedef float    f32x4_t __attribute__((ext_vector_type(4)));

__device__ __forceinline__ float sigmoidf_(float x) {
    return 1.0f / (1.0f + __expf(-x));
}
__device__ __forceinline__ float tanhf_(float x) {
    return 1.0f - 2.0f / (1.0f + __expf(2.0f * x));
}

// ---------------- fused: MFMA GRU recurrence (blocks 0..249) +
//                  XCD-sharded packed histogram (blocks 250..8249) --------
// Histogram: one u32 atomic per edge packs sum(w) fixed-point + count; the
// returned old value's count IS the edge's rank in its dst bucket -> direct
// write se32[d*SLOTS+rank]. Entry is 4 B: (s:17 | w:15 fixed 2^-15).
// NEW (round 8): XCD sharding. Consecutive blockIdx round-robin across the
// 8 XCDs (dispatch heuristic), so all hist blocks with the same blockIdx%8
// share an XCD. Slice ownership = blockIdx%8 puts every dc/se32 atomic and
// scatter store into a 64KB+2.05MB slice that stays resident in the LOCAL
// XCD L2: atomic RMWs go local (~150cy vs ~400+ cross-XCD), and a bucket
// line absorbs ranks 0..15 before ONE writeback instead of ping-ponging
// dirty across dies (rounds 2/4: cross-XCD scatter = 65 MB line-granular
// WRITE, the recHist pole). Cost: 8x scan of the dst stream (+32 MB
// streaming reads). Correctness does NOT depend on the XCD mapping.
// Round-3 lesson: no __threadfence() in hot per-block paths (= buffer_inv).
// Recurrence: one block (4 waves) owns 16 nodes for all 32 timesteps; wave
// wv owns the 16-feature stripe of each gate. Weight B-frags in VGPRs; LDS
// only a 2x(16x72) fp16 ping-pong for the C->A h transpose; 1 barrier/step.
// Fragment layouts (gfx950 16x16x32): A[m=lane&15][k=quad*8+j],
// B[k=quad*8+j][n=lane&15], C[m=quad*4+reg][n=lane&15].
__global__ __launch_bounds__(256) void k_recHist(
    const float* __restrict__ x, const float* __restrict__ Wih,
    const float* __restrict__ Whh, const float* __restrict__ bih,
    const float* __restrict__ bhh, const float* __restrict__ Wg,
    _Float16* __restrict__ xwh,
    const int* __restrict__ ei, const float* __restrict__ ea,
    unsigned* __restrict__ dc, unsigned* __restrict__ se32)
{
    __shared__ __align__(16) _Float16 hbuf[2][16 * 72];   // stride 72: conflict-free

    const int tid = threadIdx.x;

    if (blockIdx.x >= REC_BLOCKS) {
        // -------- sharded histogram path --------
        const int i     = blockIdx.x - REC_BLOCKS;   // 0..7999
        const int f     = blockIdx.x & 7;            // slice owner (= XCD hint)
        const int chunk = i >> 3;                    // 0..999; complete & distinct
                                                     // per family (i=i0+8k -> k)
        const int dlo   = f * SLICE;
#pragma unroll 1
        for (int p = 0; p < CHUNK / 256; ++p) {
            int e = chunk * CHUNK + p * 256 + tid;   // < ECOUNT by construction
            int d = ei[ECOUNT + e];
            if ((unsigned)(d - dlo) < (unsigned)SLICE) {
                int s = ei[e];
                float w = ea[e];
                unsigned q = (unsigned)(w * 32768.0f + 0.5f); q = q > 32767u ? 32767u : q;
                unsigned fx = (unsigned)(w * SUM_SCALE + 0.5f);
                unsigned old = atomicAdd(&dc[d], (1u << CNT_SHIFT) | fx);
                int r = (int)(old >> CNT_SHIFT);
                if (r < SLOTS)   // safety clamp; statistically never taken
                    se32[d * SLOTS + r] = ((unsigned)s << 15) | q;
            }
        }
        return;
    }

    // -------- recurrence path --------
    const int lane = tid & 63;
    const int wv   = tid >> 6;       // feature tile 0..3
    const int c    = lane & 15;
    const int quad = lane >> 4;
    const int n0   = blockIdx.x * 16;

    auto makeB = [&](const float* W, int row, int k0) -> half8_t {
        const float4* p = (const float4*)(W + (size_t)row * HDIM + k0);
        float4 u = p[0], v = p[1];
        half8_t h;
        h[0] = (_Float16)u.x; h[1] = (_Float16)u.y; h[2] = (_Float16)u.z; h[3] = (_Float16)u.w;
        h[4] = (_Float16)v.x; h[5] = (_Float16)v.y; h[6] = (_Float16)v.z; h[7] = (_Float16)v.w;
        return h;
    };

    half8_t Bxr[2], Bxz[2], Bxn[2], Bhr[2], Bhz[2], Bhn[2], Bw[2];
#pragma unroll
    for (int kt = 0; kt < 2; ++kt) {
        int k0 = kt * 32 + quad * 8;
        Bxr[kt] = makeB(Wih, wv * 16 + c, k0);
        Bxz[kt] = makeB(Wih, 64 + wv * 16 + c, k0);
        Bxn[kt] = makeB(Wih, 128 + wv * 16 + c, k0);
        Bhr[kt] = makeB(Whh, wv * 16 + c, k0);
        Bhz[kt] = makeB(Whh, 64 + wv * 16 + c, k0);
        Bhn[kt] = makeB(Whh, 128 + wv * 16 + c, k0);
        Bw[kt]  = makeB(Wg, wv * 16 + c, k0);
    }

    const int f = wv * 16 + c;
    const float brz_r = bih[f] + bhh[f];
    const float brz_z = bih[64 + f] + bhh[64 + f];
    const float bin_  = bih[128 + f];
    const float bhn_  = bhh[128 + f];

    float hreg[4] = {0.f, 0.f, 0.f, 0.f};
    half8_t ah[2];

    const float* xp = x + (size_t)(n0 + c) * (TSTEPS * HDIM) + quad * 8;

    float4 xq0[4], xq1[4];
    {
        const float* p0 = xp;
        xq0[0] = *(const float4*)(p0);      xq0[1] = *(const float4*)(p0 + 4);
        xq0[2] = *(const float4*)(p0 + 32); xq0[3] = *(const float4*)(p0 + 36);
        const float* p1 = xp + HDIM;
        xq1[0] = *(const float4*)(p1);      xq1[1] = *(const float4*)(p1 + 4);
        xq1[2] = *(const float4*)(p1 + 32); xq1[3] = *(const float4*)(p1 + 36);
    }

    auto step = [&](int t, float4* xq) {
        half8_t ax[2];
#pragma unroll
        for (int kt = 0; kt < 2; ++kt) {
            float4 u = xq[kt * 2], v = xq[kt * 2 + 1];
            half8_t a;
            a[0] = (_Float16)u.x; a[1] = (_Float16)u.y; a[2] = (_Float16)u.z; a[3] = (_Float16)u.w;
            a[4] = (_Float16)v.x; a[5] = (_Float16)v.y; a[6] = (_Float16)v.z; a[7] = (_Float16)v.w;
            ax[kt] = a;
        }
        if (t + 2 < TSTEPS) {
            const float* pt = xp + (size_t)(t + 2) * HDIM;
            xq[0] = *(const float4*)(pt);      xq[1] = *(const float4*)(pt + 4);
            xq[2] = *(const float4*)(pt + 32); xq[3] = *(const float4*)(pt + 36);
        }

        f32x4_t Cr  = (f32x4_t){0.f, 0.f, 0.f, 0.f};
        f32x4_t Cz  = (f32x4_t){0.f, 0.f, 0.f, 0.f};
        f32x4_t Cnx = (f32x4_t){0.f, 0.f, 0.f, 0.f};
        f32x4_t Cnh = (f32x4_t){0.f, 0.f, 0.f, 0.f};

#pragma unroll
        for (int kt = 0; kt < 2; ++kt) {
            Cr  = __builtin_amdgcn_mfma_f32_16x16x32_f16(ax[kt], Bxr[kt], Cr, 0, 0, 0);
            Cz  = __builtin_amdgcn_mfma_f32_16x16x32_f16(ax[kt], Bxz[kt], Cz, 0, 0, 0);
            Cnx = __builtin_amdgcn_mfma_f32_16x16x32_f16(ax[kt], Bxn[kt], Cnx, 0, 0, 0);
        }
        if (t > 0) {
#pragma unroll
            for (int kt = 0; kt < 2; ++kt) {
                Cr  = __builtin_amdgcn_mfma_f32_16x16x32_f16(ah[kt], Bhr[kt], Cr, 0, 0, 0);
                Cz  = __builtin_amdgcn_mfma_f32_16x16x32_f16(ah[kt], Bhz[kt], Cz, 0, 0, 0);
                Cnh = __builtin_amdgcn_mfma_f32_16x16x32_f16(ah[kt], Bhn[kt], Cnh, 0, 0, 0);
            }
        }

        _Float16* hb = hbuf[t & 1];
#pragma unroll
        for (int r = 0; r < 4; ++r) {
            float rr = sigmoidf_(Cr[r] + brz_r);
            float zz = sigmoidf_(Cz[r] + brz_z);
            float nn = tanhf_(Cnx[r] + bin_ + rr * (Cnh[r] + bhn_));
            float hn = (1.0f - zz) * nn + zz * hreg[r];
            hreg[r] = hn;
            hb[(quad * 4 + r) * 72 + f] = (_Float16)hn;
        }

        __syncthreads();

#pragma unroll
        for (int kt = 0; kt < 2; ++kt)
            ah[kt] = *(half8_t*)&hb[c * 72 + kt * 32 + quad * 8];

        f32x4_t Cw = (f32x4_t){0.f, 0.f, 0.f, 0.f};
#pragma unroll
        for (int kt = 0; kt < 2; ++kt)
            Cw = __builtin_amdgcn_mfma_f32_16x16x32_f16(ah[kt], Bw[kt], Cw, 0, 0, 0);

#pragma unroll
        for (int r = 0; r < 4; ++r) {
            int row = (n0 + quad * 4 + r) * TSTEPS + t;
            xwh[(size_t)row * HDIM + f] = (_Float16)Cw[r];
        }
    };

#pragma unroll 1
    for (int tt = 0; tt < TSTEPS; tt += 2) {
        step(tt, xq0);
        step(tt + 1, xq1);
    }
}

// ---------------- in-place pre-scale: xwh[r][:] *= dis[r] -----------------
// dis[r] = rsqrt(1 + sum_w) from the packed dc. After this pass the gather
// needs NO per-src dc lookup: y[d] = dis[d]*(xws[d] + sum_e w_e*xws[src_e]).
// BW-bound: ~33 MB, ~8 us.
__global__ __launch_bounds__(256) void k_scale(
    _Float16* __restrict__ xwh, const unsigned* __restrict__ dc)
{
    const int t = blockIdx.x * 256 + threadIdx.x;      // 8 fp16 per thread
    const int row = t >> 3;
    const float dd = rsqrtf(1.0f + (float)(dc[row] & SUM_MASK) * 0x1p-18f);
    half8_t v = *(half8_t*)&xwh[(size_t)t * 8];
#pragma unroll
    for (int i = 0; i < 8; ++i) v[i] = (_Float16)((float)v[i] * dd);
    *(half8_t*)&xwh[(size_t)t * 8] = v;
}

// ---------------- bucket gather fused with per-(b,t) reduction ------------
// Each wave owns ROWS_PER_WAVE=5 consecutive dst rows (block: 20 rows; 20|500
// so a block never straddles a bt bucket). One accumulator per wave across
// its rows -> 64 S-atomics per block (25-way collisions). Inner loop per
// edge is just bucket->row-load->fma (coef packed in the bucket entry; src
// rows pre-scaled by k_scale). 8-way unroll (mean deg = 8) keeps up to 8
// independent 128 B row loads in flight per wave. No fences.
__global__ __launch_bounds__(256) void k_gather(
    const _Float16* __restrict__ xws, const unsigned* __restrict__ dc,
    const unsigned* __restrict__ se32, float* __restrict__ S)
{
    const int tid  = threadIdx.x;
    const int lane = tid & 63;
    const int wv   = tid >> 6;
    const int d0   = blockIdx.x * ROWS_PER_BLOCK + wv * ROWS_PER_WAVE;

    // hoist independent per-row scalars: packed histogram + self-loop value
    unsigned pk[ROWS_PER_WAVE];
    float    sf[ROWS_PER_WAVE];
#pragma unroll
    for (int i = 0; i < ROWS_PER_WAVE; ++i) pk[i] = dc[d0 + i];
#pragma unroll
    for (int i = 0; i < ROWS_PER_WAVE; ++i)
        sf[i] = (float)xws[(size_t)(d0 + i) * HDIM + lane];

    float acc = 0.f;
#pragma unroll
    for (int i = 0; i < ROWS_PER_WAVE; ++i) {
        const int d = d0 + i;
        const float dd = rsqrtf(1.0f + (float)(pk[i] & SUM_MASK) * 0x1p-18f);
        int cnt = (int)(pk[i] >> CNT_SHIFT);
        cnt = cnt < SLOTS ? cnt : SLOTS;
        const unsigned* bkt = se32 + (size_t)d * SLOTS;

        float a0 = sf[i];        // self-loop term: xws[d] (dd applied at end)
        float a1 = 0.f, a2 = 0.f, a3 = 0.f;
        int j = 0;
        for (; j + 8 <= cnt; j += 8) {
            uint4 qa = *(const uint4*)(bkt + j);
            uint4 qb = *(const uint4*)(bkt + j + 4);
            float v0 = (float)xws[(size_t)(qa.x >> 15) * HDIM + lane];
            float v1 = (float)xws[(size_t)(qa.y >> 15) * HDIM + lane];
            float v2 = (float)xws[(size_t)(qa.z >> 15) * HDIM + lane];
            float v3 = (float)xws[(size_t)(qa.w >> 15) * HDIM + lane];
            float v4 = (float)xws[(size_t)(qb.x >> 15) * HDIM + lane];
            float v5 = (float)xws[(size_t)(qb.y >> 15) * HDIM + lane];
            float v6 = (float)xws[(size_t)(qb.z >> 15) * HDIM + lane];
            float v7 = (float)xws[(size_t)(qb.w >> 15) * HDIM + lane];
            a0 = fmaf((float)(qa.x & 0x7FFFu) * 0x1p-15f, v0, a0);
            a1 = fmaf((float)(qa.y & 0x7FFFu) * 0x1p-15f, v1, a1);
            a2 = fmaf((float)(qa.z & 0x7FFFu) * 0x1p-15f, v2, a2);
            a3 = fmaf((float)(qa.w & 0x7FFFu) * 0x1p-15f, v3, a3);
            a0 = fmaf((float)(qb.x & 0x7FFFu) * 0x1p-15f, v4, a0);
            a1 = fmaf((float)(qb.y & 0x7FFFu) * 0x1p-15f, v5, a1);
            a2 = fmaf((float)(qb.z & 0x7FFFu) * 0x1p-15f, v6, a2);
            a3 = fmaf((float)(qb.w & 0x7FFFu) * 0x1p-15f, v7, a3);
        }
        for (; j + 4 <= cnt; j += 4) {
            uint4 q = *(const uint4*)(bkt + j);
            float v0 = (float)xws[(size_t)(q.x >> 15) * HDIM + lane];
            float v1 = (float)xws[(size_t)(q.y >> 15) * HDIM + lane];
            float v2 = (float)xws[(size_t)(q.z >> 15) * HDIM + lane];
            float v3 = (float)xws[(size_t)(q.w >> 15) * HDIM + lane];
            a0 = fmaf((float)(q.x & 0x7FFFu) * 0x1p-15f, v0, a0);
            a1 = fmaf((float)(q.y & 0x7FFFu) * 0x1p-15f, v1, a1);
            a2 = fmaf((float)(q.z & 0x7FFFu) * 0x1p-15f, v2, a2);
            a3 = fmaf((float)(q.w & 0x7FFFu) * 0x1p-15f, v3, a3);
        }
        for (; j < cnt; ++j) {
            unsigned u = bkt[j];
            a0 = fmaf((float)(u & 0x7FFFu) * 0x1p-15f,
                      (float)xws[(size_t)(u >> 15) * HDIM + lane], a0);
        }
        acc = fmaf(dd, (a0 + a1) + (a2 + a3), acc);
    }

    __shared__ float red[256];
    red[tid] = acc;
    __syncthreads();
    if (tid < 64) {
        float s = red[tid] + red[64 + tid] + red[128 + tid] + red[192 + tid];
        atomicAdd(&S[((blockIdx.x * ROWS_PER_BLOCK) / NNEUR) * HDIM + tid], s);  // bt = d/500
    }
}

// ---------------- attention MLP + pooling + FC head (one block) ----------------
__global__ __launch_bounds__(256) void k_final(
    const float* __restrict__ S, const float* __restrict__ W1,
    const float* __restrict__ W2, const float* __restrict__ fcW,
    const float* __restrict__ fcb, float* __restrict__ out)
{
    __shared__ float xt[256];
    __shared__ float a1[128];
    __shared__ float attn[256];
    __shared__ float pooled[512];
    const int tid = threadIdx.x;

    {
        float s = 0.f;
        const float* p = S + tid * 64;
#pragma unroll
        for (int hh = 0; hh < 64; ++hh) s += p[hh];
        xt[tid] = s * (1.0f / 32000.0f);
    }
    __syncthreads();
    if (tid < 128) {
        int b = tid >> 4, i = tid & 15;
        float s = 0.f;
#pragma unroll
        for (int t = 0; t < 32; ++t) s += xt[b * 32 + t] * W1[i * 32 + t];
        a1[tid] = fmaxf(s, 0.f);
    }
    __syncthreads();
    {
        int b = tid >> 5, t = tid & 31;
        float s = 0.f;
#pragma unroll
        for (int i = 0; i < 16; ++i) s += a1[b * 16 + i] * W2[t * 16 + i];
        attn[tid] = 1.0f / (1.0f + __expf(-s));
    }
    __syncthreads();
    for (int o = tid; o < 512; o += 256) {
        int b = o >> 6, h = o & 63;
        float s = 0.f;
#pragma unroll
        for (int t = 0; t < 32; ++t) s += attn[b * 32 + t] * S[(b * 32 + t) * 64 + h];
        pooled[o] = s;
    }
    __syncthreads();
    if (tid < BATCHB * NSTEPS) {
        int b = tid / NSTEPS, st = tid % NSTEPS;
        float acc = fcb[st];
#pragma unroll
        for (int h = 0; h < 64; ++h) acc += pooled[b * 64 + h] * fcW[st * 64 + h];
        out[b * NSTEPS + st] = acc;
    }
}

extern "C" void kernel_launch(void* const* d_in, const int* in_sizes, int n_in,
                              void* d_out, int out_size, void* d_ws, size_t ws_size,
                              hipStream_t stream) {
    const float* x   = (const float*)d_in[0];
    const int*   ei  = (const int*)  d_in[1];
    const float* ea  = (const float*)d_in[2];
    // d_in[3] = batch: unused by the reference computation
    const float* Wih = (const float*)d_in[4];
    const float* Whh = (const float*)d_in[5];
    const float* bih = (const float*)d_in[6];
    const float* bhh = (const float*)d_in[7];
    const float* Wg  = (const float*)d_in[8];
    const float* W1  = (const float*)d_in[9];
    const float* W2  = (const float*)d_in[10];
    const float* fcW = (const float*)d_in[11];
    const float* fcb = (const float*)d_in[12];
    float* out = (float*)d_out;

    // workspace layout (~33.3 MB); dc and S adjacent -> one memset clears both
    char* p = (char*)d_ws;
    unsigned* dc = (unsigned*)p;   p += sizeof(unsigned) * NTOT;                                    // 512 KB
    float* S = (float*)p;          p += sizeof(float) * 256 * HDIM;                                 // 64 KB
    unsigned* se32 = (unsigned*)p; p += sizeof(unsigned) * (size_t)NTOT * SLOTS;                    // 16.38 MB
    _Float16* xwh = (_Float16*)p;  p += sizeof(_Float16) * (size_t)NTOT * HDIM;                     // 16.38 MB

    hipMemsetAsync(dc, 0, sizeof(unsigned) * NTOT + sizeof(float) * 256 * HDIM, stream);
    k_recHist <<<REC_BLOCKS + HIST_BLOCKS, 256, 0, stream>>>(
        x, Wih, Whh, bih, bhh, Wg, xwh, ei, ea, dc, se32);
    k_scale   <<<SCALE_BLOCKS, 256, 0, stream>>>(xwh, dc);
    k_gather  <<<GATHER_BLOCKS, 256, 0, stream>>>(xwh, dc, se32, S);
    k_final   <<<1, 256, 0, stream>>>(S, W1, W2, fcW, fcb, out);
}